// Round 10
// baseline (320.973 us; speedup 1.0000x reference)
//
#include <hip/hip_runtime.h>
#include <hip/hip_bf16.h>
#include <stdint.h>

#define D_MODEL 1024
#define D_INNER 2048
#define NEXP 8
#define TOPK 2
#define T256 40
#define T128 72

typedef float f32x4 __attribute__((ext_vector_type(4)));
typedef short bf16x8 __attribute__((ext_vector_type(8)));

#define MEMFENCE asm volatile("" ::: "memory")
#define SB __builtin_amdgcn_sched_barrier(0)
#define LGKM0 asm volatile("s_waitcnt lgkmcnt(0)" ::: "memory")
#define VM0 asm volatile("s_waitcnt vmcnt(0)" ::: "memory")
#define VM6 asm volatile("s_waitcnt vmcnt(6)" ::: "memory")
#define BAR __builtin_amdgcn_s_barrier()

__device__ __forceinline__ unsigned short f2b(float f) {
    union { float f; uint32_t u; } v; v.f = f;
    uint32_t u = v.u;
    return (unsigned short)((u + 0x7fffu + ((u >> 16) & 1u)) >> 16);
}

__device__ __forceinline__ void gl_lds16(const void* g, void* l) {
    __builtin_amdgcn_global_load_lds((const __attribute__((address_space(1))) void*)g,
                                     (__attribute__((address_space(3))) void*)l, 16, 0, 0);
}

// ------- cast+transpose all 3 weights: [E][K][N] fp32 -> [E][N][K] bf16 -------
__global__ __launch_bounds__(256) void tcast3_kernel(
    const float* __restrict__ gw, const float* __restrict__ uw, const float* __restrict__ dw,
    unsigned short* __restrict__ gT, unsigned short* __restrict__ uT, unsigned short* __restrict__ dT)
{
    __shared__ unsigned short S[64][68];
    int which = blockIdx.z >> 3;
    int e = blockIdx.z & 7;
    const float* in; unsigned short* out; int K, N;
    if (which == 0)      { in = gw; out = gT; K = D_MODEL; N = D_INNER; }
    else if (which == 1) { in = uw; out = uT; K = D_MODEL; N = D_INNER; }
    else                 { in = dw; out = dT; K = D_INNER; N = D_MODEL; }
    int n0 = blockIdx.x * 64, k0 = blockIdx.y * 64;
    if (n0 >= N || k0 >= K) return;
    const float* ib = in + (size_t)e * K * N;
    unsigned short* ob = out + (size_t)e * N * K;
    int tid = threadIdx.x;
    int kk = tid >> 4, nn4 = (tid & 15) * 4;
#pragma unroll
    for (int j = 0; j < 4; j++) {
        int k = kk + 16 * j;
        float4 v = *(const float4*)&ib[(size_t)(k0 + k) * N + n0 + nn4];
        ushort4 s; s.x = f2b(v.x); s.y = f2b(v.y); s.z = f2b(v.z); s.w = f2b(v.w);
        *(ushort4*)&S[k][nn4] = s;
    }
    __syncthreads();
    int nn = tid >> 4, kk4 = (tid & 15) * 4;
#pragma unroll
    for (int j = 0; j < 4; j++) {
        int n = nn + 16 * j;
        ushort4 s;
        s.x = S[kk4 + 0][n]; s.y = S[kk4 + 1][n];
        s.z = S[kk4 + 2][n]; s.w = S[kk4 + 3][n];
        *(ushort4*)&ob[(size_t)(n0 + n) * K + k0 + kk4] = s;
    }
}

// ---------------- router (+ fused x->bf16 cast): 1 wave per token ----------------
__global__ __launch_bounds__(64) void router_kernel(
    const float* __restrict__ x, const float* __restrict__ rw,
    const float* __restrict__ rb, unsigned short* __restrict__ xb,
    int* __restrict__ top_i, float* __restrict__ top_w, int T)
{
    int t = blockIdx.x;
    if (t >= T) return;
    int l = threadIdx.x;
    float xv[16];
#pragma unroll
    for (int i = 0; i < 16; i++) xv[i] = x[(size_t)t * D_MODEL + l + 64 * i];
#pragma unroll
    for (int i = 0; i < 16; i++) xb[(size_t)t * D_MODEL + l + 64 * i] = f2b(xv[i]);
    float logit[NEXP];
#pragma unroll
    for (int e = 0; e < NEXP; e++) {
        float acc = 0.f;
#pragma unroll
        for (int i = 0; i < 16; i++) acc += xv[i] * rw[e * D_MODEL + l + 64 * i];
#pragma unroll
        for (int s = 32; s > 0; s >>= 1) acc += __shfl_xor(acc, s, 64);
        logit[e] = acc + rb[e];
    }
    if (l == 0) {
        int i0 = 0; float m0 = logit[0];
#pragma unroll
        for (int e = 1; e < NEXP; e++) if (logit[e] > m0) { m0 = logit[e]; i0 = e; }
        int i1 = -1; float m1 = -3.0e38f;
#pragma unroll
        for (int e = 0; e < NEXP; e++) {
            if (e == i0) continue;
            if (logit[e] > m1) { m1 = logit[e]; i1 = e; }
        }
        float w0 = 1.f / (1.f + expf(m1 - m0));
        top_i[t * 2 + 0] = i0; top_i[t * 2 + 1] = i1;
        top_w[t * 2 + 0] = w0; top_w[t * 2 + 1] = 1.f - w0;
    }
}

// ---------------- bucket build + compact tile worklists ----------------
__global__ __launch_bounds__(256) void bucket_kernel(
    const int* __restrict__ top_i, const float* __restrict__ top_w,
    int* __restrict__ meta, int* __restrict__ tok_of_slot,
    float* __restrict__ w_of_slot, int T)
{
    __shared__ int cnt[256][NEXP];
    __shared__ int pre[256][NEXP];
    __shared__ int tot[NEXP];
    __shared__ int off[NEXP + 1];
    int tid = threadIdx.x;
    int per = (T + 255) / 256;
    int t0 = tid * per;
    for (int e = 0; e < NEXP; e++) cnt[tid][e] = 0;
    for (int t = t0; t < t0 + per && t < T; t++)
        for (int k = 0; k < TOPK; k++) cnt[tid][top_i[t * 2 + k]]++;
    __syncthreads();
    if (tid < NEXP) {
        int run = 0;
        for (int i = 0; i < 256; i++) { pre[i][tid] = run; run += cnt[i][tid]; }
        tot[tid] = run;
    }
    __syncthreads();
    if (tid == 0) {
        off[0] = 0;
        for (int e = 0; e < NEXP; e++) off[e + 1] = off[e] + tot[e];
        for (int e = 0; e <= NEXP; e++) meta[e] = off[e];
        int nt = 0;
        for (int e = 0; e < NEXP; e++)
            for (int r = off[e]; r < off[e + 1]; r += 256)
                meta[16 + nt++] = (e << 16) | r;
        meta[11] = nt;
        for (; nt < T256; nt++) meta[16 + nt] = -1;
        nt = 0;
        for (int e = 0; e < NEXP; e++)
            for (int r = off[e]; r < off[e + 1]; r += 128)
                meta[64 + nt++] = (e << 16) | r;
        meta[12] = nt;
        for (; nt < T128; nt++) meta[64 + nt] = -1;
    }
    __syncthreads();
    int lc[NEXP];
#pragma unroll
    for (int e = 0; e < NEXP; e++) lc[e] = 0;
    for (int t = t0; t < t0 + per && t < T; t++) {
        for (int k = 0; k < TOPK; k++) {
            int e = top_i[t * 2 + k];
            int slot = off[e] + pre[tid][e] + lc[e]++;
            tok_of_slot[slot] = t;
            w_of_slot[slot] = top_w[t * 2 + k];
        }
    }
}

// ======================= gate+up GEMM + swiglu -> H =======================
// Persistent 256 blocks x 512 thr. Tile M=256 x F=128; 8 waves = 2M x 2sel(g/u) x 2F,
// per-wave 128x64 of one matrix. BK=64, 2 x 64KB LDS. 4 fine phases per K-tile:
// {small ds_read batch + 2-3 stage issues + BAR + lgkm0 + 16 MFMA + BAR}.
// vmcnt(0) only at P3 (kt+1 ops all >=1 phase old). Epilogue: u via LDS -> silu fuse.
__global__ __launch_bounds__(512, 1) void moe_gate_up(
    const unsigned short* __restrict__ xb, const unsigned short* __restrict__ wgT,
    const unsigned short* __restrict__ wuT, const int* __restrict__ meta,
    const int* __restrict__ tok_of_slot, unsigned short* __restrict__ H,
    int* __restrict__ ctr)
{
    extern __shared__ __align__(16) unsigned short lds[];   // 2*32768 ush + epilogue f32
    __shared__ int sm_wid;

    int tid = threadIdx.x, wv = tid >> 6, lane = tid & 63;
    int lrow = lane & 15, kgrp = lane >> 4, sw = lrow & 7;
    int mh = wv >> 2, sel = (wv >> 1) & 1, fh = wv & 1;
    int c = tid & 7, rr = tid >> 3;
    int cx8 = (c ^ (rr & 7)) * 8;
    int co0 = 8 * (kgrp ^ sw);
    int co1 = 8 * ((4 + kgrp) ^ sw);
    int dL = wv * 512 + lane * 8;        // per-thread linear LDS dest (ushorts), + j*4096

    int aoff[8], boff[4];
#pragma unroll
    for (int i = 0; i < 8; i++) aoff[i] = (mh * 128 + i * 16 + lrow) * 64;
    int bbase = 16384 + sel * 8192;
#pragma unroll
    for (int i = 0; i < 4; i++) boff[i] = bbase + (fh * 64 + i * 16 + lrow) * 64;

    int n256 = meta[11];
    int nwork = n256 * 16;

    for (;;) {
        __syncthreads();
        if (tid == 0) sm_wid = atomicAdd(ctr, 1);
        __syncthreads();
        int wid = sm_wid;
        if (wid >= nwork) break;
        int strip = wid / n256, tix = wid - strip * n256;
        int packed = meta[16 + tix];
        int e = packed >> 16, row0 = packed & 0xffff;
        int Mloc = min(256, meta[e + 1] - row0);
        int f0 = strip * 128;

        const unsigned short* sA[4];
#pragma unroll
        for (int j = 0; j < 4; j++) {
            int row = j * 64 + rr;
            int slot = row0 + ((row < Mloc) ? row : 0);
            sA[j] = xb + (size_t)tok_of_slot[slot] * D_MODEL + cx8;
        }
        const unsigned short *sG[2], *sU[2];
#pragma unroll
        for (int j = 0; j < 2; j++) {
            int row = j * 64 + rr;
            size_t wb = (size_t)e * D_MODEL * D_INNER + (size_t)(f0 + row) * D_MODEL + cx8;
            sG[j] = wgT + wb; sU[j] = wuT + wb;
        }

        f32x4 acc[8][4];
#pragma unroll
        for (int i = 0; i < 8; i++)
#pragma unroll
            for (int j = 0; j < 4; j++) acc[i][j] = (f32x4){0.f, 0.f, 0.f, 0.f};

        // prologue: stage kt0 fully (8 ops)
        {
            unsigned short* b = lds;
#pragma unroll
            for (int j = 0; j < 4; j++) gl_lds16(sA[j], b + j * 4096 + dL);
#pragma unroll
            for (int j = 0; j < 2; j++) {
                gl_lds16(sG[j], b + 16384 + j * 4096 + dL);
                gl_lds16(sU[j], b + 24576 + j * 4096 + dL);
            }
        }
        MEMFENCE; VM0; BAR; MEMFENCE;

        for (int kt = 0; kt < 16; ++kt) {
            const unsigned short* buf = lds + (kt & 1) * 32768;
            unsigned short* nb = lds + ((kt + 1) & 1) * 32768;
            int kk = (kt + 1) * 64;
            bool pf = (kt + 1) < 16;
            bf16x8 Aq[4][2], B0[2][2], B1[2][2];

            // ---- P0: read Aq(lo)+Bp0, stage 3, MFMA fm0-3 x fn0-1 ----
#pragma unroll
            for (int i = 0; i < 4; i++) {
                Aq[i][0] = *(const bf16x8*)(buf + aoff[i] + co0);
                Aq[i][1] = *(const bf16x8*)(buf + aoff[i] + co1);
            }
#pragma unroll
            for (int j = 0; j < 2; j++) {
                B0[j][0] = *(const bf16x8*)(buf + boff[j] + co0);
                B0[j][1] = *(const bf16x8*)(buf + boff[j] + co1);
            }
            if (pf) {
                gl_lds16(sA[0] + kk, nb + dL);
                gl_lds16(sA[1] + kk, nb + 4096 + dL);
                gl_lds16(sG[0] + kk, nb + 16384 + dL);
            }
            SB; BAR; LGKM0; SB;
            __builtin_amdgcn_s_setprio(1);
#pragma unroll
            for (int i = 0; i < 4; i++)
#pragma unroll
                for (int j = 0; j < 2; j++) {
                    acc[i][j] = __builtin_amdgcn_mfma_f32_16x16x32_bf16(Aq[i][0], B0[j][0], acc[i][j], 0, 0, 0);
                    acc[i][j] = __builtin_amdgcn_mfma_f32_16x16x32_bf16(Aq[i][1], B0[j][1], acc[i][j], 0, 0, 0);
                }
            __builtin_amdgcn_s_setprio(0);
            SB; BAR;

            // ---- P1: read Bp1, stage 3, MFMA fm0-3 x fn2-3 ----
#pragma unroll
            for (int j = 0; j < 2; j++) {
                B1[j][0] = *(const bf16x8*)(buf + boff[2 + j] + co0);
                B1[j][1] = *(const bf16x8*)(buf + boff[2 + j] + co1);
            }
            if (pf) {
                gl_lds16(sA[2] + kk, nb + 8192 + dL);
                gl_lds16(sA[3] + kk, nb + 12288 + dL);
                gl_lds16(sU[0] + kk, nb + 24576 + dL);
            }
            SB; BAR; LGKM0; SB;
            __builtin_amdgcn_s_setprio(1);
#pragma unroll
            for (int i = 0; i < 4; i++)
#pragma unroll
                for (int j = 0; j < 2; j++) {
                    acc[i][2 + j] = __builtin_amdgcn_mfma_f32_16x16x32_bf16(Aq[i][0], B1[j][0], acc[i][2 + j], 0, 0, 0);
                    acc[i][2 + j] = __builtin_amdgcn_mfma_f32_16x16x32_bf16(Aq[i][1], B1[j][1], acc[i][2 + j], 0, 0, 0);
                }
            __builtin_amdgcn_s_setprio(0);
            SB; BAR;

            // ---- P2: read Aq(hi), stage 2, MFMA fm4-7 x fn0-1 ----
#pragma unroll
            for (int i = 0; i < 4; i++) {
                Aq[i][0] = *(const bf16x8*)(buf + aoff[4 + i] + co0);
                Aq[i][1] = *(const bf16x8*)(buf + aoff[4 + i] + co1);
            }
            if (pf) {
                gl_lds16(sG[1] + kk, nb + 16384 + 4096 + dL);
                gl_lds16(sU[1] + kk, nb + 24576 + 4096 + dL);
            }
            SB; BAR; LGKM0; SB;
            __builtin_amdgcn_s_setprio(1);
#pragma unroll
            for (int i = 0; i < 4; i++)
#pragma unroll
                for (int j = 0; j < 2; j++) {
                    acc[4 + i][j] = __builtin_amdgcn_mfma_f32_16x16x32_bf16(Aq[i][0], B0[j][0], acc[4 + i][j], 0, 0, 0);
                    acc[4 + i][j] = __builtin_amdgcn_mfma_f32_16x16x32_bf16(Aq[i][1], B0[j][1], acc[4 + i][j], 0, 0, 0);
                }
            __builtin_amdgcn_s_setprio(0);
            SB; BAR;

            // ---- P3: MFMA fm4-7 x fn2-3, then vmcnt(0) for kt+1 buffer ----
            __builtin_amdgcn_s_setprio(1);
#pragma unroll
            for (int i = 0; i < 4; i++)
#pragma unroll
                for (int j = 0; j < 2; j++) {
                    acc[4 + i][2 + j] = __builtin_amdgcn_mfma_f32_16x16x32_bf16(Aq[i][0], B1[j][0], acc[4 + i][2 + j], 0, 0, 0);
                    acc[4 + i][2 + j] = __builtin_amdgcn_mfma_f32_16x16x32_bf16(Aq[i][1], B1[j][1], acc[4 + i][2 + j], 0, 0, 0);
                }
            __builtin_amdgcn_s_setprio(0);
            SB; VM0; BAR; MEMFENCE;
        }

        // epilogue: u-waves publish acc via LDS [128][65] f32; g-waves fuse+store
        float* reg = (float*)lds + (mh * 2 + fh) * 8320;
        if (sel == 1) {
#pragma unroll
            for (int fm = 0; fm < 8; fm++)
#pragma unroll
                for (int fn = 0; fn < 4; fn++)
#pragma unroll
                    for (int r = 0; r < 4; r++)
                        reg[(fm * 16 + kgrp * 4 + r) * 65 + fn * 16 + lrow] = acc[fm][fn][r];
        }
        __syncthreads();
        if (sel == 0) {
#pragma unroll
            for (int fm = 0; fm < 8; fm++)
#pragma unroll
                for (int fn = 0; fn < 4; fn++)
#pragma unroll
                    for (int r = 0; r < 4; r++) {
                        int row = fm * 16 + kgrp * 4 + r;
                        int m = mh * 128 + row;
                        if (m < Mloc) {
                            float g = acc[fm][fn][r];
                            float u = reg[row * 65 + fn * 16 + lrow];
                            float h = g / (1.f + __expf(-g)) * u;
                            H[(size_t)(row0 + m) * D_INNER + f0 + fh * 64 + fn * 16 + lrow] = f2b(h);
                        }
                    }
        }
    }
}

// ======================= down GEMM + weighted scatter =======================
// Persistent 256 blocks x 512 thr. Tile M=128 x N=256; 8 waves = 2M x 4N,
// per-wave 64x64. BK=64, 3 x 48KB LDS ring, 2-deep prefetch, counted vmcnt(6).
// 2 fine phases per K-tile, 16 MFMA each.
__global__ __launch_bounds__(512, 1) void moe_down(
    const unsigned short* __restrict__ H, const unsigned short* __restrict__ wdT,
    const int* __restrict__ meta, const int* __restrict__ tok_of_slot,
    const float* __restrict__ w_of_slot, float* __restrict__ out, int S2,
    int* __restrict__ ctr)
{
    extern __shared__ __align__(16) unsigned short lds[];   // 3 * 24576 ushorts
    __shared__ int toks[128];
    __shared__ float wts[128];
    __shared__ int sm_wid;

    int tid = threadIdx.x, wv = tid >> 6, lane = tid & 63;
    int lrow = lane & 15, kgrp = lane >> 4, sw = lrow & 7;
    int mh = wv >> 2, nh = wv & 3;
    int c = tid & 7, rr = tid >> 3;
    int cx8 = (c ^ (rr & 7)) * 8;
    int co0 = 8 * (kgrp ^ sw);
    int co1 = 8 * ((4 + kgrp) ^ sw);
    int dL = wv * 512 + lane * 8;

    int aoff[4], boff[4];
#pragma unroll
    for (int i = 0; i < 4; i++) aoff[i] = (mh * 64 + i * 16 + lrow) * 64;
#pragma unroll
    for (int i = 0; i < 4; i++) boff[i] = 8192 + (nh * 64 + i * 16 + lrow) * 64;

    int n128 = meta[12];
    int nwork = n128 * 4;

    for (;;) {
        __syncthreads();
        if (tid == 0) sm_wid = atomicAdd(ctr, 1);
        __syncthreads();
        int wid = sm_wid;
        if (wid >= nwork) break;
        int dstrip = wid / n128, tix = wid - dstrip * n128;
        int packed = meta[64 + tix];
        int e = packed >> 16, row0 = packed & 0xffff;
        int Mloc = min(128, meta[e + 1] - row0);
        int d0 = dstrip * 256;

        if (tid < 128) {
            bool v = tid < Mloc;
            toks[tid] = v ? tok_of_slot[row0 + tid] : 0;
            wts[tid] = v ? w_of_slot[row0 + tid] : 0.f;
        }

        const unsigned short* sA[2];
        const unsigned short* sBv[4];
#pragma unroll
        for (int j = 0; j < 2; j++) {
            int row = j * 64 + rr;
            int slot = min(row0 + row, S2 - 1);
            sA[j] = H + (size_t)slot * D_INNER + cx8;
        }
#pragma unroll
        for (int j = 0; j < 4; j++) {
            int row = j * 64 + rr;
            sBv[j] = wdT + (size_t)e * D_INNER * D_MODEL + (size_t)(d0 + row) * D_INNER + cx8;
        }

        f32x4 acc[4][4];
#pragma unroll
        for (int i = 0; i < 4; i++)
#pragma unroll
            for (int j = 0; j < 4; j++) acc[i][j] = (f32x4){0.f, 0.f, 0.f, 0.f};

        // prologue: stage kt0, kt1 (6 ops each)
#pragma unroll
        for (int u = 0; u < 2; u++) {
            unsigned short* b = lds + u * 24576;
            int kk = u * 64;
#pragma unroll
            for (int j = 0; j < 2; j++) gl_lds16(sA[j] + kk, b + j * 4096 + dL);
#pragma unroll
            for (int j = 0; j < 4; j++) gl_lds16(sBv[j] + kk, b + 8192 + j * 4096 + dL);
        }
        MEMFENCE; VM6; BAR; MEMFENCE;

        for (int kt = 0; kt < 32; ++kt) {
            const unsigned short* buf = lds + (kt % 3) * 24576;
            unsigned short* nb = lds + ((kt + 2) % 3) * 24576;
            int kk = (kt + 2) * 64;
            bool pf = (kt + 2) < 32;
            bf16x8 Aq[4][2], B0[2][2], B1[2][2];

            // ---- P0: read Aq + Bp0, stage 3 (kt+2), MFMA fn0-1 ----
#pragma unroll
            for (int i = 0; i < 4; i++) {
                Aq[i][0] = *(const bf16x8*)(buf + aoff[i] + co0);
                Aq[i][1] = *(const bf16x8*)(buf + aoff[i] + co1);
            }
#pragma unroll
            for (int j = 0; j < 2; j++) {
                B0[j][0] = *(const bf16x8*)(buf + boff[j] + co0);
                B0[j][1] = *(const bf16x8*)(buf + boff[j] + co1);
            }
            if (pf) {
                gl_lds16(sA[0] + kk, nb + dL);
                gl_lds16(sA[1] + kk, nb + 4096 + dL);
                gl_lds16(sBv[0] + kk, nb + 8192 + dL);
            }
            SB; BAR; LGKM0; SB;
            __builtin_amdgcn_s_setprio(1);
#pragma unroll
            for (int i = 0; i < 4; i++)
#pragma unroll
                for (int j = 0; j < 2; j++) {
                    acc[i][j] = __builtin_amdgcn_mfma_f32_16x16x32_bf16(Aq[i][0], B0[j][0], acc[i][j], 0, 0, 0);
                    acc[i][j] = __builtin_amdgcn_mfma_f32_16x16x32_bf16(Aq[i][1], B0[j][1], acc[i][j], 0, 0, 0);
                }
            __builtin_amdgcn_s_setprio(0);
            SB; BAR;

            // ---- P1: read Bp1, stage 3, MFMA fn2-3, counted vmcnt ----
#pragma unroll
            for (int j = 0; j < 2; j++) {
                B1[j][0] = *(const bf16x8*)(buf + boff[2 + j] + co0);
                B1[j][1] = *(const bf16x8*)(buf + boff[2 + j] + co1);
            }
            if (pf) {
                gl_lds16(sBv[1] + kk, nb + 8192 + 4096 + dL);
                gl_lds16(sBv[2] + kk, nb + 8192 + 8192 + dL);
                gl_lds16(sBv[3] + kk, nb + 8192 + 12288 + dL);
            }
            SB; BAR; LGKM0; SB;
            __builtin_amdgcn_s_setprio(1);
#pragma unroll
            for (int i = 0; i < 4; i++)
#pragma unroll
                for (int j = 0; j < 2; j++) {
                    acc[i][2 + j] = __builtin_amdgcn_mfma_f32_16x16x32_bf16(Aq[i][0], B1[j][0], acc[i][2 + j], 0, 0, 0);
                    acc[i][2 + j] = __builtin_amdgcn_mfma_f32_16x16x32_bf16(Aq[i][1], B1[j][1], acc[i][2 + j], 0, 0, 0);
                }
            __builtin_amdgcn_s_setprio(0);
            SB;
            if (pf) { VM6; } else { VM0; }   // wait kt+1 landed; kt+2 stays in flight
            BAR; MEMFENCE;
        }

        // epilogue: weighted atomic scatter (2 adds per out element total)
#pragma unroll
        for (int fm = 0; fm < 4; fm++)
#pragma unroll
            for (int fn = 0; fn < 4; fn++)
#pragma unroll
                for (int r = 0; r < 4; r++) {
                    int m = mh * 64 + fm * 16 + kgrp * 4 + r;
                    if (m < Mloc) {
                        int n = d0 + nh * 64 + fn * 16 + lrow;
                        atomicAdd(&out[(size_t)toks[m] * D_MODEL + n], wts[m] * acc[fm][fn][r]);
                    }
                }
    }
}

extern "C" void kernel_launch(void* const* d_in, const int* in_sizes, int n_in,
                              void* d_out, int out_size, void* d_ws, size_t ws_size,
                              hipStream_t stream) {
    const float* x  = (const float*)d_in[0];
    const float* rw = (const float*)d_in[1];
    const float* rb = (const float*)d_in[2];
    const float* gw = (const float*)d_in[3];
    const float* uw = (const float*)d_in[4];
    const float* dw = (const float*)d_in[5];
    float* out = (float*)d_out;

    int T = in_sizes[0] / D_MODEL;   // 4096
    int S2 = 2 * T;                   // 8192 slots

    char* ws = (char*)d_ws;
    size_t cur = 0;
    auto take = [&](size_t bytes) { char* p = ws + cur; cur = (cur + bytes + 255) & ~(size_t)255; return p; };
    int*   ctrs  = (int*)take(256);
    int*   top_i = (int*)take((size_t)S2 * 4);
    float* top_w = (float*)take((size_t)S2 * 4);
    int*   meta  = (int*)take(1024);
    int*   tos   = (int*)take((size_t)S2 * 4);
    float* wos   = (float*)take((size_t)S2 * 4);
    unsigned short* xb  = (unsigned short*)take((size_t)T * D_MODEL * 2);
    unsigned short* wgT = (unsigned short*)take((size_t)NEXP * D_MODEL * D_INNER * 2);
    unsigned short* wuT = (unsigned short*)take((size_t)NEXP * D_MODEL * D_INNER * 2);
    unsigned short* wdT = (unsigned short*)take((size_t)NEXP * D_MODEL * D_INNER * 2);
    unsigned short* H   = (unsigned short*)take((size_t)S2 * D_INNER * 2);

    static const int GU_LDS = 133120;       // max(2*32768*2, 4*8320*4)
    static const int DN_LDS = 3 * 24576 * 2; // 147456
    hipFuncSetAttribute((const void*)moe_gate_up,
                        hipFuncAttributeMaxDynamicSharedMemorySize, GU_LDS);
    hipFuncSetAttribute((const void*)moe_down,
                        hipFuncAttributeMaxDynamicSharedMemorySize, DN_LDS);

    hipMemsetAsync(ctrs, 0, 256, stream);
    hipMemsetAsync(d_out, 0, (size_t)out_size * sizeof(float), stream);

    tcast3_kernel<<<dim3(32, 32, 24), 256, 0, stream>>>(gw, uw, dw, wgT, wuT, wdT);
    router_kernel<<<T, 64, 0, stream>>>(x, rw, rb, xb, top_i, top_w, T);
    bucket_kernel<<<1, 256, 0, stream>>>(top_i, top_w, meta, tos, wos, T);

    moe_gate_up<<<256, 512, GU_LDS, stream>>>(xb, wgT, wuT, meta, tos, H, &ctrs[0]);
    moe_down<<<256, 512, DN_LDS, stream>>>(H, wdT, meta, tos, wos, out, S2, &ctrs[1]);
}

// Round 11
// 272.149 us; speedup vs baseline: 1.1794x; 1.1794x over previous
//
#include <hip/hip_runtime.h>
#include <hip/hip_bf16.h>
#include <stdint.h>

#define D_MODEL 1024
#define D_INNER 2048
#define NEXP 8
#define TOPK 2
#define T256 40
#define T128 72

typedef float f32x4 __attribute__((ext_vector_type(4)));
typedef short bf16x8 __attribute__((ext_vector_type(8)));

#define MEMFENCE asm volatile("" ::: "memory")
#define SB __builtin_amdgcn_sched_barrier(0)
#define LGKM0 asm volatile("s_waitcnt lgkmcnt(0)" ::: "memory")
#define VM0 asm volatile("s_waitcnt vmcnt(0)" ::: "memory")
#define VM4 asm volatile("s_waitcnt vmcnt(4)" ::: "memory")
#define BAR __builtin_amdgcn_s_barrier()
#define SW2(r) (((r) >> 1) & 3)

__device__ __forceinline__ unsigned short f2b(float f) {
    union { float f; uint32_t u; } v; v.f = f;
    uint32_t u = v.u;
    return (unsigned short)((u + 0x7fffu + ((u >> 16) & 1u)) >> 16);
}

__device__ __forceinline__ void gl_lds16(const void* g, void* l) {
    __builtin_amdgcn_global_load_lds((const __attribute__((address_space(1))) void*)g,
                                     (__attribute__((address_space(3))) void*)l, 16, 0, 0);
}

// ------- cast+transpose all 3 weights: [E][K][N] fp32 -> [E][N][K] bf16 -------
__global__ __launch_bounds__(256) void tcast3_kernel(
    const float* __restrict__ gw, const float* __restrict__ uw, const float* __restrict__ dw,
    unsigned short* __restrict__ gT, unsigned short* __restrict__ uT, unsigned short* __restrict__ dT)
{
    __shared__ unsigned short S[64][68];
    int which = blockIdx.z >> 3;
    int e = blockIdx.z & 7;
    const float* in; unsigned short* out; int K, N;
    if (which == 0)      { in = gw; out = gT; K = D_MODEL; N = D_INNER; }
    else if (which == 1) { in = uw; out = uT; K = D_MODEL; N = D_INNER; }
    else                 { in = dw; out = dT; K = D_INNER; N = D_MODEL; }
    int n0 = blockIdx.x * 64, k0 = blockIdx.y * 64;
    if (n0 >= N || k0 >= K) return;
    const float* ib = in + (size_t)e * K * N;
    unsigned short* ob = out + (size_t)e * N * K;
    int tid = threadIdx.x;
    int kk = tid >> 4, nn4 = (tid & 15) * 4;
#pragma unroll
    for (int j = 0; j < 4; j++) {
        int k = kk + 16 * j;
        float4 v = *(const float4*)&ib[(size_t)(k0 + k) * N + n0 + nn4];
        ushort4 s; s.x = f2b(v.x); s.y = f2b(v.y); s.z = f2b(v.z); s.w = f2b(v.w);
        *(ushort4*)&S[k][nn4] = s;
    }
    __syncthreads();
    int nn = tid >> 4, kk4 = (tid & 15) * 4;
#pragma unroll
    for (int j = 0; j < 4; j++) {
        int n = nn + 16 * j;
        ushort4 s;
        s.x = S[kk4 + 0][n]; s.y = S[kk4 + 1][n];
        s.z = S[kk4 + 2][n]; s.w = S[kk4 + 3][n];
        *(ushort4*)&ob[(size_t)(n0 + n) * K + k0 + kk4] = s;
    }
}

// ---------------- router (+ fused x->bf16 cast): 1 wave per token ----------------
__global__ __launch_bounds__(64) void router_kernel(
    const float* __restrict__ x, const float* __restrict__ rw,
    const float* __restrict__ rb, unsigned short* __restrict__ xb,
    int* __restrict__ top_i, float* __restrict__ top_w, int T)
{
    int t = blockIdx.x;
    if (t >= T) return;
    int l = threadIdx.x;
    float xv[16];
#pragma unroll
    for (int i = 0; i < 16; i++) xv[i] = x[(size_t)t * D_MODEL + l + 64 * i];
#pragma unroll
    for (int i = 0; i < 16; i++) xb[(size_t)t * D_MODEL + l + 64 * i] = f2b(xv[i]);
    float logit[NEXP];
#pragma unroll
    for (int e = 0; e < NEXP; e++) {
        float acc = 0.f;
#pragma unroll
        for (int i = 0; i < 16; i++) acc += xv[i] * rw[e * D_MODEL + l + 64 * i];
#pragma unroll
        for (int s = 32; s > 0; s >>= 1) acc += __shfl_xor(acc, s, 64);
        logit[e] = acc + rb[e];
    }
    if (l == 0) {
        int i0 = 0; float m0 = logit[0];
#pragma unroll
        for (int e = 1; e < NEXP; e++) if (logit[e] > m0) { m0 = logit[e]; i0 = e; }
        int i1 = -1; float m1 = -3.0e38f;
#pragma unroll
        for (int e = 0; e < NEXP; e++) {
            if (e == i0) continue;
            if (logit[e] > m1) { m1 = logit[e]; i1 = e; }
        }
        float w0 = 1.f / (1.f + expf(m1 - m0));
        top_i[t * 2 + 0] = i0; top_i[t * 2 + 1] = i1;
        top_w[t * 2 + 0] = w0; top_w[t * 2 + 1] = 1.f - w0;
    }
}

// ---------------- bucket build + compact tile worklists ----------------
__global__ __launch_bounds__(256) void bucket_kernel(
    const int* __restrict__ top_i, const float* __restrict__ top_w,
    int* __restrict__ meta, int* __restrict__ tok_of_slot,
    float* __restrict__ w_of_slot, int T)
{
    __shared__ int cnt[256][NEXP];
    __shared__ int pre[256][NEXP];
    __shared__ int tot[NEXP];
    __shared__ int off[NEXP + 1];
    int tid = threadIdx.x;
    int per = (T + 255) / 256;
    int t0 = tid * per;
    for (int e = 0; e < NEXP; e++) cnt[tid][e] = 0;
    for (int t = t0; t < t0 + per && t < T; t++)
        for (int k = 0; k < TOPK; k++) cnt[tid][top_i[t * 2 + k]]++;
    __syncthreads();
    if (tid < NEXP) {
        int run = 0;
        for (int i = 0; i < 256; i++) { pre[i][tid] = run; run += cnt[i][tid]; }
        tot[tid] = run;
    }
    __syncthreads();
    if (tid == 0) {
        off[0] = 0;
        for (int e = 0; e < NEXP; e++) off[e + 1] = off[e] + tot[e];
        for (int e = 0; e <= NEXP; e++) meta[e] = off[e];
        int nt = 0;
        for (int e = 0; e < NEXP; e++)
            for (int r = off[e]; r < off[e + 1]; r += 256)
                meta[16 + nt++] = (e << 16) | r;
        meta[11] = nt;
        for (; nt < T256; nt++) meta[16 + nt] = -1;
        nt = 0;
        for (int e = 0; e < NEXP; e++)
            for (int r = off[e]; r < off[e + 1]; r += 128)
                meta[64 + nt++] = (e << 16) | r;
        meta[12] = nt;
        for (; nt < T128; nt++) meta[64 + nt] = -1;
    }
    __syncthreads();
    int lc[NEXP];
#pragma unroll
    for (int e = 0; e < NEXP; e++) lc[e] = 0;
    for (int t = t0; t < t0 + per && t < T; t++) {
        for (int k = 0; k < TOPK; k++) {
            int e = top_i[t * 2 + k];
            int slot = off[e] + pre[tid][e] + lc[e]++;
            tok_of_slot[slot] = t;
            w_of_slot[slot] = top_w[t * 2 + k];
        }
    }
}

// ======================= gate+up GEMM + swiglu -> H =======================
// 256 thr / 4 waves, tile M=128 x F=64 carrying g AND u. Per wave 64x64 of ONE
// matrix (wm = wv>>1, sel = wv&1): acc = 64 regs. BK=32, 3 x 16KB LDS ring ->
// 3 blocks/CU (independent blocks overlap on each SIMD). Counted vmcnt(4).
__global__ __launch_bounds__(256, 3) void moe_gate_up(
    const unsigned short* __restrict__ xb, const unsigned short* __restrict__ wgT,
    const unsigned short* __restrict__ wuT, const int* __restrict__ meta,
    const int* __restrict__ tok_of_slot, unsigned short* __restrict__ H)
{
    extern __shared__ __align__(16) unsigned short lds[];   // 3 * 8192 ushorts

    int lin = blockIdx.x;
    int strip = (lin & 7) * 4 + ((lin >> 3) & 3);   // lin%8 = XCD -> 4 strips each
    int tix = lin >> 5;
    int packed = meta[64 + tix];
    if (packed < 0) return;
    int e = packed >> 16, row0 = packed & 0xffff;
    int Mloc = min(128, meta[e + 1] - row0);
    int f0 = strip * 64;

    int tid = threadIdx.x, wv = tid >> 6, lane = tid & 63;
    int lrow = lane & 15, kgrp = lane >> 4;
    int sel = wv & 1, wm = wv >> 1;
    int co = 8 * (kgrp ^ SW2(lrow));

    // staging sources (per thread: A x2, Bg x1, Bu x1 = 4 gl_lds/K-tile)
    const unsigned short* sA[2];
    int dA[2];
#pragma unroll
    for (int j = 0; j < 2; j++) {
        int idx = j * 256 + tid;
        int r = idx >> 2, c = idx & 3;
        int slot = row0 + ((r < Mloc) ? r : 0);
        sA[j] = xb + (size_t)tok_of_slot[slot] * D_MODEL + 8 * (c ^ SW2(r));
        dA[j] = idx * 8;
    }
    const unsigned short *sG, *sU;
    {
        int r = tid >> 2, c = tid & 3;
        size_t wb = (size_t)e * D_MODEL * D_INNER + (size_t)(f0 + r) * D_MODEL + 8 * (c ^ SW2(r));
        sG = wgT + wb; sU = wuT + wb;
    }

    int aoff[4], boff[4];
#pragma unroll
    for (int i = 0; i < 4; i++) aoff[i] = (wm * 64 + i * 16 + lrow) * 32 + co;
    int bb = sel ? 6144 : 4096;
#pragma unroll
    for (int i = 0; i < 4; i++) boff[i] = bb + (i * 16 + lrow) * 32 + co;

    f32x4 acc[4][4];
#pragma unroll
    for (int i = 0; i < 4; i++)
#pragma unroll
        for (int j = 0; j < 4; j++) acc[i][j] = (f32x4){0.f, 0.f, 0.f, 0.f};

    auto stage = [&](int u) {   // A 8KB + Bg 4KB + Bu 4KB = 16KB block-wide
        int kk = u * 32;
        unsigned short* b = lds + (u % 3) * 8192;
        gl_lds16(sA[0] + kk, b + dA[0]);
        gl_lds16(sA[1] + kk, b + dA[1]);
        gl_lds16(sG + kk, b + 4096 + tid * 8);
        gl_lds16(sU + kk, b + 6144 + tid * 8);
    };

    bf16x8 a[4], bfr[4];
    auto load_frags = [&](int u) {   // 8 ds_read_b128
        const unsigned short* b = lds + (u % 3) * 8192;
#pragma unroll
        for (int i = 0; i < 4; i++) a[i] = *(const bf16x8*)(b + aoff[i]);
#pragma unroll
        for (int i = 0; i < 4; i++) bfr[i] = *(const bf16x8*)(b + boff[i]);
    };

    const int NT = D_MODEL / 32;   // 32
    stage(0); stage(1);
    MEMFENCE;
    VM4;                            // tile 0 landed; tile 1 in flight
    BAR; MEMFENCE;
    load_frags(0);

    for (int t = 0; t < NT; ++t) {
        if (t + 2 < NT) stage(t + 2);
        SB;
        __builtin_amdgcn_s_setprio(1);
#pragma unroll
        for (int i = 0; i < 4; i++)
#pragma unroll
            for (int j = 0; j < 4; j++)
                acc[i][j] = __builtin_amdgcn_mfma_f32_16x16x32_bf16(a[i], bfr[j], acc[i][j], 0, 0, 0);
        __builtin_amdgcn_s_setprio(0);
        SB;
        LGKM0;
        if (t + 2 < NT) { VM4; } else { VM0; }   // t+1 landed; t+2 stays in flight
        BAR; MEMFENCE;
        if (t + 1 < NT) load_frags(t + 1);
    }

    // epilogue: u-waves (sel=1) publish acc via LDS f32 [64][65]; g-waves fuse silu
    __syncthreads();
    float* ex = (float*)lds;
    if (sel == 1) {
        float* dst = ex + wm * 4160;
#pragma unroll
        for (int i = 0; i < 4; i++)
#pragma unroll
            for (int j = 0; j < 4; j++)
#pragma unroll
                for (int r = 0; r < 4; r++)
                    dst[(i * 16 + kgrp * 4 + r) * 65 + j * 16 + lrow] = acc[i][j][r];
    }
    __syncthreads();
    if (sel == 0) {
        const float* src = ex + wm * 4160;
#pragma unroll
        for (int i = 0; i < 4; i++)
#pragma unroll
            for (int j = 0; j < 4; j++)
#pragma unroll
                for (int r = 0; r < 4; r++) {
                    int row = i * 16 + kgrp * 4 + r;
                    int m = wm * 64 + row;
                    if (m < Mloc) {
                        float g = acc[i][j][r];
                        float u = src[row * 65 + j * 16 + lrow];
                        float h = g / (1.f + __expf(-g)) * u;
                        H[(size_t)(row0 + m) * D_INNER + f0 + j * 16 + lrow] = f2b(h);
                    }
                }
    }
}

// ======================= down GEMM + weighted scatter =======================
// 256 thr / 4 waves, tile M=128 x N=128 (wm x wn, per-wave 64x64). BK=32,
// 3 x 16KB LDS ring, 3 blocks/CU, counted vmcnt(4). Atomic scatter epilogue.
__global__ __launch_bounds__(256, 3) void moe_down(
    const unsigned short* __restrict__ H, const unsigned short* __restrict__ wdT,
    const int* __restrict__ meta, const int* __restrict__ tok_of_slot,
    const float* __restrict__ w_of_slot, float* __restrict__ out, int S2)
{
    extern __shared__ __align__(16) unsigned short lds[];   // 3 * 8192 ushorts
    __shared__ int toks[128];
    __shared__ float wts[128];

    int lin = blockIdx.x;
    int d0 = (lin & 7) * 128;      // lin%8 = XCD -> 4MB L2-resident wdT slice
    int tix = lin >> 3;
    int packed = meta[64 + tix];
    if (packed < 0) return;
    int e = packed >> 16, row0 = packed & 0xffff;
    int Mloc = min(128, meta[e + 1] - row0);

    int tid = threadIdx.x, wv = tid >> 6, lane = tid & 63;
    int lrow = lane & 15, kgrp = lane >> 4;
    int wn = wv & 1, wm = wv >> 1;
    int co = 8 * (kgrp ^ SW2(lrow));

    if (tid < 128) {
        bool v = tid < Mloc;
        toks[tid] = v ? tok_of_slot[row0 + tid] : 0;
        wts[tid] = v ? w_of_slot[row0 + tid] : 0.f;
    }

    const unsigned short* sA[2];
    const unsigned short* sB[2];
    int dA[2];
#pragma unroll
    for (int j = 0; j < 2; j++) {
        int idx = j * 256 + tid;
        int r = idx >> 2, c = idx & 3;
        int slot = min(row0 + r, S2 - 1);
        sA[j] = H + (size_t)slot * D_INNER + 8 * (c ^ SW2(r));
        sB[j] = wdT + (size_t)e * D_INNER * D_MODEL + (size_t)(d0 + r) * D_INNER + 8 * (c ^ SW2(r));
        dA[j] = idx * 8;
    }

    int aoff[4], boff[4];
#pragma unroll
    for (int i = 0; i < 4; i++) aoff[i] = (wm * 64 + i * 16 + lrow) * 32 + co;
#pragma unroll
    for (int i = 0; i < 4; i++) boff[i] = 4096 + (wn * 64 + i * 16 + lrow) * 32 + co;

    f32x4 acc[4][4];
#pragma unroll
    for (int i = 0; i < 4; i++)
#pragma unroll
        for (int j = 0; j < 4; j++) acc[i][j] = (f32x4){0.f, 0.f, 0.f, 0.f};

    auto stage = [&](int u) {   // A 8KB + B 8KB = 16KB block-wide (4 ops/thread)
        int kk = u * 32;
        unsigned short* b = lds + (u % 3) * 8192;
        gl_lds16(sA[0] + kk, b + dA[0]);
        gl_lds16(sA[1] + kk, b + dA[1]);
        gl_lds16(sB[0] + kk, b + 4096 + dA[0]);
        gl_lds16(sB[1] + kk, b + 4096 + dA[1]);
    };

    bf16x8 a[4], bfr[4];
    auto load_frags = [&](int u) {
        const unsigned short* b = lds + (u % 3) * 8192;
#pragma unroll
        for (int i = 0; i < 4; i++) a[i] = *(const bf16x8*)(b + aoff[i]);
#pragma unroll
        for (int i = 0; i < 4; i++) bfr[i] = *(const bf16x8*)(b + boff[i]);
    };

    const int NT = D_INNER / 32;   // 64
    stage(0); stage(1);
    MEMFENCE;
    VM4;
    BAR; MEMFENCE;
    load_frags(0);

    for (int t = 0; t < NT; ++t) {
        if (t + 2 < NT) stage(t + 2);
        SB;
        __builtin_amdgcn_s_setprio(1);
#pragma unroll
        for (int i = 0; i < 4; i++)
#pragma unroll
            for (int j = 0; j < 4; j++)
                acc[i][j] = __builtin_amdgcn_mfma_f32_16x16x32_bf16(a[i], bfr[j], acc[i][j], 0, 0, 0);
        __builtin_amdgcn_s_setprio(0);
        SB;
        LGKM0;
        if (t + 2 < NT) { VM4; } else { VM0; }
        BAR; MEMFENCE;
        if (t + 1 < NT) load_frags(t + 1);
    }

#pragma unroll
    for (int i = 0; i < 4; i++)
#pragma unroll
        for (int j = 0; j < 4; j++)
#pragma unroll
            for (int r = 0; r < 4; r++) {
                int m = wm * 64 + i * 16 + kgrp * 4 + r;
                if (m < Mloc) {
                    int n = d0 + wn * 64 + j * 16 + lrow;
                    atomicAdd(&out[(size_t)toks[m] * D_MODEL + n], wts[m] * acc[i][j][r]);
                }
            }
}

extern "C" void kernel_launch(void* const* d_in, const int* in_sizes, int n_in,
                              void* d_out, int out_size, void* d_ws, size_t ws_size,
                              hipStream_t stream) {
    const float* x  = (const float*)d_in[0];
    const float* rw = (const float*)d_in[1];
    const float* rb = (const float*)d_in[2];
    const float* gw = (const float*)d_in[3];
    const float* uw = (const float*)d_in[4];
    const float* dw = (const float*)d_in[5];
    float* out = (float*)d_out;

    int T = in_sizes[0] / D_MODEL;   // 4096
    int S2 = 2 * T;                   // 8192 slots

    char* ws = (char*)d_ws;
    size_t cur = 0;
    auto take = [&](size_t bytes) { char* p = ws + cur; cur = (cur + bytes + 255) & ~(size_t)255; return p; };
    int*   top_i = (int*)take((size_t)S2 * 4);
    float* top_w = (float*)take((size_t)S2 * 4);
    int*   meta  = (int*)take(1024);
    int*   tos   = (int*)take((size_t)S2 * 4);
    float* wos   = (float*)take((size_t)S2 * 4);
    unsigned short* xb  = (unsigned short*)take((size_t)T * D_MODEL * 2);
    unsigned short* wgT = (unsigned short*)take((size_t)NEXP * D_MODEL * D_INNER * 2);
    unsigned short* wuT = (unsigned short*)take((size_t)NEXP * D_MODEL * D_INNER * 2);
    unsigned short* wdT = (unsigned short*)take((size_t)NEXP * D_MODEL * D_INNER * 2);
    unsigned short* H   = (unsigned short*)take((size_t)S2 * D_INNER * 2);

    static const int RING_LDS = 3 * 8192 * 2;   // 49152 B
    hipFuncSetAttribute((const void*)moe_gate_up,
                        hipFuncAttributeMaxDynamicSharedMemorySize, RING_LDS);
    hipFuncSetAttribute((const void*)moe_down,
                        hipFuncAttributeMaxDynamicSharedMemorySize, RING_LDS);

    hipMemsetAsync(d_out, 0, (size_t)out_size * sizeof(float), stream);

    tcast3_kernel<<<dim3(32, 32, 24), 256, 0, stream>>>(gw, uw, dw, wgT, wuT, wdT);
    router_kernel<<<T, 64, 0, stream>>>(x, rw, rb, xb, top_i, top_w, T);
    bucket_kernel<<<1, 256, 0, stream>>>(top_i, top_w, meta, tos, wos, T);

    moe_gate_up<<<T128 * 32, 256, RING_LDS, stream>>>(xb, wgT, wuT, meta, tos, H);
    moe_down<<<T128 * 8, 256, RING_LDS, stream>>>(H, wdT, meta, tos, wos, out, S2);
}